// Round 6
// baseline (121.687 us; speedup 1.0000x reference)
//
#include <hip/hip_runtime.h>

#define RES 300
#define NC 8          // channels per plane
#define KF 24         // 3*NC features
#define AP 32         // output dim
#define PX 152        // packed table dim (covers x0,y0 in [148, 299])
#define PBASE 148
#define LTROWS 152    // line-table rows 148..299
#define LTS 12        // LDS line-table row stride (16B aligned, spreads banks)
#define CH 4          // chunks (of 256 points) per block

typedef float f4 __attribute__((ext_vector_type(4)));
typedef _Float16 h8 __attribute__((ext_vector_type(8)));

// ---- prologue 1: row-paired fp16 table packed2[3][PX][PX][16] ---------------
// entry(i,py,px) = texel(y,x)[8ch] ++ texel(y+1,x)[8ch], 32 B contiguous.
// A bilinear footprint = entries (px0, px0+1) = 64 contiguous bytes -> ~1.5
// unique 64-B lines per plane-sample instead of ~2.5. Table 2.22 MB (L2-res).
__global__ __launch_bounds__(256) void build_packed2(const float* __restrict__ planes,
                                                     _Float16* __restrict__ packed2) {
    int idx = blockIdx.x * blockDim.x + threadIdx.x;   // over 3*PX*PX
    if (idx >= 3 * PX * PX) return;
    int px = idx % PX;
    int t  = idx / PX;
    int py = t % PX;
    int i  = t / PX;
    int x  = PBASE + px;
    int y0 = PBASE + py;
    int y1 = min(y0 + 1, RES - 1);         // row 299 duplicated; never selected
    h8 v0, v1;
#pragma unroll
    for (int c = 0; c < NC; ++c) {
        v0[c] = (_Float16)planes[((i * NC + c) * RES + y0) * RES + x];
        v1[c] = (_Float16)planes[((i * NC + c) * RES + y1) * RES + x];
    }
    _Float16* dst = packed2 + (size_t)idx * 16;
    *(h8*)(dst + 0) = v0;
    *(h8*)(dst + 8) = v1;
}

// ---- prologue 2: lt[3][LTROWS][NC] = 0.5*(col149+col150), rows 148..299 -----
// (fp32 — keeps the line factor exact; lives in LDS during main)
__global__ __launch_bounds__(256) void build_lt(const float* __restrict__ planes,
                                                float* __restrict__ lt) {
    int idx = blockIdx.x * blockDim.x + threadIdx.x;   // over 3*LTROWS*NC
    if (idx >= 3 * LTROWS * NC) return;
    int c = idx % NC;
    int t = idx / NC;          // t = i*LTROWS + r
    int r = t % LTROWS;
    int i = t / LTROWS;
    int y = PBASE + r;
    const float* row = planes + ((i * NC + c) * RES + y) * RES;
    lt[idx] = 0.5f * (row[149] + row[150]);
}

// 'size' is a Python scalar; harness may pass int32 or float32 bits.
__device__ __forceinline__ float decode_scalar(const void* p) {
    int b = *(const int*)p;
    if (b > 0 && b < (1 << 23)) return (float)b;   // small positive int
    return __int_as_float(b);                      // float bit pattern
}

// ---- main -------------------------------------------------------------------
// 256 thr; LDS = lt (21.9 KB) + quarter-block staging (9.2 KB) ≈ 31.1 KB
// -> 5 blocks/CU, 20 waves/CU.
__global__ __launch_bounds__(256, 4) void tensorf_main(
    const float* __restrict__ inputs, const float* __restrict__ W,
    const _Float16* __restrict__ packed2, const float* __restrict__ lt,
    const void* __restrict__ size_p, float* __restrict__ out, int N)
{
    __shared__ __align__(16) float lt_s[3 * LTROWS * LTS];  // stride-12 rows
    __shared__ __align__(16) float ob[64 * 36];             // quarter-block rows

    int t = threadIdx.x;
    for (int idx = t; idx < 3 * LTROWS * NC; idx += 256) {
        int c  = idx & 7;
        int rr = idx >> 3;                  // i*LTROWS + r
        lt_s[rr * LTS + c] = lt[idx];
    }
    __syncthreads();

    float inv_s = 1.0f / decode_scalar(size_p);

    for (int chunk = 0; chunk < CH; ++chunk) {
        int n0 = (blockIdx.x * CH + chunk) * 256;
        int n  = n0 + t;

        float r_out[AP];
        if (n < N) {
            float c0 = inputs[3 * n + 0] * inv_s;
            float c1 = inputs[3 * n + 1] * inv_s;
            float c2 = inputs[3 * n + 2] * inv_s;

            // MAT_MODE = {(0,1),(0,2),(1,2)}; VEC_MODE = {2,1,0}
            float gx[3] = {c0, c0, c1};
            float gy[3] = {c1, c2, c2};
            float gv[3] = {c2, c1, c0};

            float feat[KF];
#pragma unroll
            for (int i = 0; i < 3; ++i) {
                float xx = (gx[i] + 1.0f) * (0.5f * (RES - 1));
                float yy = (gy[i] + 1.0f) * (0.5f * (RES - 1));
                float xf = fminf(fmaxf(floorf(xx), 0.0f), (float)(RES - 2));
                float yf = fminf(fmaxf(floorf(yy), 0.0f), (float)(RES - 2));
                int   x0 = (int)xf, y0 = (int)yf;
                float wx = xx - xf, wy = yy - yf;
                int   px = min(max(x0 - PBASE, 0), PX - 2);
                int   py = min(max(y0 - PBASE, 0), PX - 2);

                const _Float16* e0p = packed2 + ((size_t)((i * PX + py) * PX + px)) * 16;
                h8 t00 = *(const h8*)(e0p + 0);    // (y0  , x0  )
                h8 t10 = *(const h8*)(e0p + 8);    // (y0+1, x0  )
                h8 t01 = *(const h8*)(e0p + 16);   // (y0  , x0+1)
                h8 t11 = *(const h8*)(e0p + 24);   // (y0+1, x0+1)

                float yv  = (gv[i] + 1.0f) * (0.5f * (RES - 1));
                float yvf = fminf(fmaxf(floorf(yv), 0.0f), (float)(RES - 2));
                int   y0v = (int)yvf;
                float wv  = yv - yvf;
                int   pyv = min(max(y0v - PBASE, 0), LTROWS - 2);
                const float* l0 = lt_s + (i * LTROWS + pyv) * LTS;
                f4 e0 = *(const f4*)(l0 + 0);
                f4 e1 = *(const f4*)(l0 + 4);
                f4 g0 = *(const f4*)(l0 + LTS + 0);
                f4 g1 = *(const f4*)(l0 + LTS + 4);

                float lv0[NC] = {e0.x, e0.y, e0.z, e0.w, e1.x, e1.y, e1.z, e1.w};
                float lv1[NC] = {g0.x, g0.y, g0.z, g0.w, g1.x, g1.y, g1.z, g1.w};

#pragma unroll
                for (int c = 0; c < NC; ++c) {
                    float v00 = (float)t00[c], v01 = (float)t01[c];
                    float v10 = (float)t10[c], v11 = (float)t11[c];
                    float top = v00 + wx * (v01 - v00);
                    float bot = v10 + wx * (v11 - v10);
                    float p   = top + wy * (bot - top);
                    float l   = lv0[c] + wv * (lv1[c] - lv0[c]);
                    feat[i * NC + c] = p * l;
                }
            }

            // r_out[a] = sum_k feat[k] * W[a,k]  — W thread-uniform -> s_load
#pragma unroll
            for (int a = 0; a < AP; ++a) {
                float s = 0.0f;
#pragma unroll
                for (int k = 0; k < KF; ++k)
                    s = fmaf(feat[k], W[a * KF + k], s);
                r_out[a] = s;
            }
        }

        // ---- stage + fully-coalesced nontemporal store, quarter-block at a time
#pragma unroll
        for (int h = 0; h < 4; ++h) {
            if ((t >> 6) == h && n < N) {
                int tr = t & 63;
#pragma unroll
                for (int a4 = 0; a4 < 8; ++a4)
                    *(f4*)&ob[tr * 36 + a4 * 4] =
                        f4{r_out[a4 * 4 + 0], r_out[a4 * 4 + 1],
                           r_out[a4 * 4 + 2], r_out[a4 * 4 + 3]};
            }
            __syncthreads();
            int base_n = n0 + h * 64;
#pragma unroll
            for (int k = 0; k < 2; ++k) {
                int j   = k * 256 + t;       // 0..511 over 64 rows x 8 f4
                int row = j >> 3;
                int c4  = j & 7;
                int gn  = base_n + row;
                if (gn < N) {
                    f4 v = *(const f4*)&ob[row * 36 + c4 * 4];
                    __builtin_nontemporal_store(
                        v, (f4*)(out + (size_t)gn * AP + c4 * 4));
                }
            }
            __syncthreads();
        }
    }
}

extern "C" void kernel_launch(void* const* d_in, const int* in_sizes, int n_in,
                              void* d_out, int out_size, void* d_ws, size_t ws_size,
                              hipStream_t stream) {
    const float* inputs = (const float*)d_in[0];
    const float* planes = (const float*)d_in[1];
    const float* W      = (const float*)d_in[2];
    const void*  size_p = d_in[3];
    float* out = (float*)d_out;
    int N = in_sizes[0] / 3;

    // workspace: packed2 (3*PX*PX*16 halves = 2.22 MB) | lt (3*LTROWS*NC f32)
    _Float16* packed2 = (_Float16*)d_ws;
    float*    ltbuf   = (float*)(packed2 + 3 * PX * PX * 16);

    int ppos = 3 * PX * PX;
    build_packed2<<<(ppos + 255) / 256, 256, 0, stream>>>(planes, packed2);
    int lpos = 3 * LTROWS * NC;
    build_lt<<<(lpos + 255) / 256, 256, 0, stream>>>(planes, ltbuf);
    int nblocks = (N + 256 * CH - 1) / (256 * CH);
    tensorf_main<<<nblocks, 256, 0, stream>>>(inputs, W, packed2, ltbuf,
                                              size_p, out, N);
}

// Round 7
// 112.114 us; speedup vs baseline: 1.0854x; 1.0854x over previous
//
#include <hip/hip_runtime.h>

#define RES 300
#define NC 8          // channels per plane
#define KF 24         // 3*NC features
#define AP 32         // output dim
#define PX 152        // packed table dim (covers x0,y0 in [148, 299])
#define PBASE 148
#define LTROWS 152    // line-table rows 148..299
#define LTS 12        // LDS line-table row stride (16B aligned, spreads banks)
#define CH 4          // chunks (of 256 points) per block

typedef float f4 __attribute__((ext_vector_type(4)));
typedef _Float16 h8 __attribute__((ext_vector_type(8)));

// ---- prologue 1: row-paired fp16 table packed2[3][PX][PX][16] ---------------
// entry(i,py,px) = texel(y,x)[8ch] ++ texel(y+1,x)[8ch], 32 B contiguous.
// A bilinear footprint = entries (px0, px0+1) = 64 contiguous bytes.
__global__ __launch_bounds__(256) void build_packed2(const float* __restrict__ planes,
                                                     _Float16* __restrict__ packed2) {
    int idx = blockIdx.x * blockDim.x + threadIdx.x;   // over 3*PX*PX
    if (idx >= 3 * PX * PX) return;
    int px = idx % PX;
    int t  = idx / PX;
    int py = t % PX;
    int i  = t / PX;
    int x  = PBASE + px;
    int y0 = PBASE + py;
    int y1 = min(y0 + 1, RES - 1);         // row 299 duplicated; never selected
    h8 v0, v1;
#pragma unroll
    for (int c = 0; c < NC; ++c) {
        v0[c] = (_Float16)planes[((i * NC + c) * RES + y0) * RES + x];
        v1[c] = (_Float16)planes[((i * NC + c) * RES + y1) * RES + x];
    }
    _Float16* dst = packed2 + (size_t)idx * 16;
    *(h8*)(dst + 0) = v0;
    *(h8*)(dst + 8) = v1;
}

// ---- prologue 2: lt[3][LTROWS][NC] = 0.5*(col149+col150), rows 148..299 -----
__global__ __launch_bounds__(256) void build_lt(const float* __restrict__ planes,
                                                float* __restrict__ lt) {
    int idx = blockIdx.x * blockDim.x + threadIdx.x;   // over 3*LTROWS*NC
    if (idx >= 3 * LTROWS * NC) return;
    int c = idx % NC;
    int t = idx / NC;          // t = i*LTROWS + r
    int r = t % LTROWS;
    int i = t / LTROWS;
    int y = PBASE + r;
    const float* row = planes + ((i * NC + c) * RES + y) * RES;
    lt[idx] = 0.5f * (row[149] + row[150]);
}

// 'size' is a Python scalar; harness may pass int32 or float32 bits.
__device__ __forceinline__ float decode_scalar(const void* p) {
    int b = *(const int*)p;
    if (b > 0 && b < (1 << 23)) return (float)b;   // small positive int
    return __int_as_float(b);                      // float bit pattern
}

// ---- main -------------------------------------------------------------------
// Two-phase per point: Phase A issues ALL 12 texel gathers (48 VGPR in flight),
// Phase B consumes. Disambiguates latency-serialization vs TA-throughput.
// LDS = lt (21.9 KB) + quarter-block staging (9.2 KB) ≈ 31.1 KB.
__global__ __launch_bounds__(256, 4) void tensorf_main(
    const float* __restrict__ inputs, const float* __restrict__ W,
    const _Float16* __restrict__ packed2, const float* __restrict__ lt,
    const void* __restrict__ size_p, float* __restrict__ out, int N)
{
    __shared__ __align__(16) float lt_s[3 * LTROWS * LTS];  // stride-12 rows
    __shared__ __align__(16) float ob[64 * 36];             // quarter-block rows

    int t = threadIdx.x;
    for (int idx = t; idx < 3 * LTROWS * NC; idx += 256) {
        int c  = idx & 7;
        int rr = idx >> 3;                  // i*LTROWS + r
        lt_s[rr * LTS + c] = lt[idx];
    }
    __syncthreads();

    float inv_s = 1.0f / decode_scalar(size_p);

    for (int chunk = 0; chunk < CH; ++chunk) {
        int n0 = (blockIdx.x * CH + chunk) * 256;
        int n  = n0 + t;

        float r_out[AP];
        if (n < N) {
            float c0 = inputs[3 * n + 0] * inv_s;
            float c1 = inputs[3 * n + 1] * inv_s;
            float c2 = inputs[3 * n + 2] * inv_s;

            // MAT_MODE = {(0,1),(0,2),(1,2)}; VEC_MODE = {2,1,0}
            float gxA[3] = {c0, c0, c1};
            float gyA[3] = {c1, c2, c2};
            float gvA[3] = {c2, c1, c0};

            // ---- Phase A: all addresses, then all 12 gathers issued together
            h8    tx[3][4];
            float wxA[3], wyA[3], wvA[3];
            int   pyvA[3];
#pragma unroll
            for (int i = 0; i < 3; ++i) {
                float xx = (gxA[i] + 1.0f) * (0.5f * (RES - 1));
                float yy = (gyA[i] + 1.0f) * (0.5f * (RES - 1));
                float xf = fminf(fmaxf(floorf(xx), 0.0f), (float)(RES - 2));
                float yf = fminf(fmaxf(floorf(yy), 0.0f), (float)(RES - 2));
                int   x0 = (int)xf, y0 = (int)yf;
                wxA[i] = xx - xf;
                wyA[i] = yy - yf;
                int px = min(max(x0 - PBASE, 0), PX - 2);
                int py = min(max(y0 - PBASE, 0), PX - 2);

                const _Float16* ep = packed2 + ((size_t)((i * PX + py) * PX + px)) * 16;
                tx[i][0] = *(const h8*)(ep + 0);    // (y0  , x0  )
                tx[i][1] = *(const h8*)(ep + 8);    // (y0+1, x0  )
                tx[i][2] = *(const h8*)(ep + 16);   // (y0  , x0+1)
                tx[i][3] = *(const h8*)(ep + 24);   // (y0+1, x0+1)

                float yv  = (gvA[i] + 1.0f) * (0.5f * (RES - 1));
                float yvf = fminf(fmaxf(floorf(yv), 0.0f), (float)(RES - 2));
                wvA[i]  = yv - yvf;
                pyvA[i] = min(max((int)yvf - PBASE, 0), LTROWS - 2);
            }

            // ---- Phase B: consume (lt from LDS overlaps outstanding vmem)
            float feat[KF];
#pragma unroll
            for (int i = 0; i < 3; ++i) {
                const float* l0 = lt_s + (i * LTROWS + pyvA[i]) * LTS;
                f4 e0 = *(const f4*)(l0 + 0);
                f4 e1 = *(const f4*)(l0 + 4);
                f4 g0 = *(const f4*)(l0 + LTS + 0);
                f4 g1 = *(const f4*)(l0 + LTS + 4);
                float lv0[NC] = {e0.x, e0.y, e0.z, e0.w, e1.x, e1.y, e1.z, e1.w};
                float lv1[NC] = {g0.x, g0.y, g0.z, g0.w, g1.x, g1.y, g1.z, g1.w};

                float wx = wxA[i], wy = wyA[i], wv = wvA[i];
                float w11 = wx * wy;
                float w01 = wx - w11;            // wx*(1-wy)
                float w10 = wy - w11;            // (1-wx)*wy
                float w00 = 1.0f - wx - w10;     // (1-wx)*(1-wy)
#pragma unroll
                for (int c = 0; c < NC; ++c) {
                    float p = w00 * (float)tx[i][0][c];
                    p = fmaf(w10, (float)tx[i][1][c], p);
                    p = fmaf(w01, (float)tx[i][2][c], p);
                    p = fmaf(w11, (float)tx[i][3][c], p);
                    float l = fmaf(wv, lv1[c] - lv0[c], lv0[c]);
                    feat[i * NC + c] = p * l;
                }
            }

            // r_out[a] = sum_k feat[k] * W[a,k]  — W thread-uniform -> s_load
#pragma unroll
            for (int a = 0; a < AP; ++a) {
                float s = 0.0f;
#pragma unroll
                for (int k = 0; k < KF; ++k)
                    s = fmaf(feat[k], W[a * KF + k], s);
                r_out[a] = s;
            }
        }

        // ---- stage + fully-coalesced nontemporal store, quarter-block at a time
#pragma unroll
        for (int h = 0; h < 4; ++h) {
            if ((t >> 6) == h && n < N) {
                int tr = t & 63;
#pragma unroll
                for (int a4 = 0; a4 < 8; ++a4)
                    *(f4*)&ob[tr * 36 + a4 * 4] =
                        f4{r_out[a4 * 4 + 0], r_out[a4 * 4 + 1],
                           r_out[a4 * 4 + 2], r_out[a4 * 4 + 3]};
            }
            __syncthreads();
            int base_n = n0 + h * 64;
#pragma unroll
            for (int k = 0; k < 2; ++k) {
                int j   = k * 256 + t;       // 0..511 over 64 rows x 8 f4
                int row = j >> 3;
                int c4  = j & 7;
                int gn  = base_n + row;
                if (gn < N) {
                    f4 v = *(const f4*)&ob[row * 36 + c4 * 4];
                    __builtin_nontemporal_store(
                        v, (f4*)(out + (size_t)gn * AP + c4 * 4));
                }
            }
            __syncthreads();
        }
    }
}

extern "C" void kernel_launch(void* const* d_in, const int* in_sizes, int n_in,
                              void* d_out, int out_size, void* d_ws, size_t ws_size,
                              hipStream_t stream) {
    const float* inputs = (const float*)d_in[0];
    const float* planes = (const float*)d_in[1];
    const float* W      = (const float*)d_in[2];
    const void*  size_p = d_in[3];
    float* out = (float*)d_out;
    int N = in_sizes[0] / 3;

    // workspace: packed2 (3*PX*PX*16 halves = 2.22 MB) | lt (3*LTROWS*NC f32)
    _Float16* packed2 = (_Float16*)d_ws;
    float*    ltbuf   = (float*)(packed2 + 3 * PX * PX * 16);

    int ppos = 3 * PX * PX;
    build_packed2<<<(ppos + 255) / 256, 256, 0, stream>>>(planes, packed2);
    int lpos = 3 * LTROWS * NC;
    build_lt<<<(lpos + 255) / 256, 256, 0, stream>>>(planes, ltbuf);
    int nblocks = (N + 256 * CH - 1) / (256 * CH);
    tensorf_main<<<nblocks, 256, 0, stream>>>(inputs, W, packed2, ltbuf,
                                              size_p, out, N);
}